// Round 1
// baseline (1037.670 us; speedup 1.0000x reference)
//
#include <hip/hip_runtime.h>
#include <hip/hip_bf16.h>
#include <math.h>

// Problem constants (B=4, S=2048 -> T=8192 tokens)
#define T_TOK 8192
#define DM    1024
#define NE    8
#define HD    4096

typedef __bf16 bf16;
typedef __attribute__((ext_vector_type(8))) __bf16 bf16x8;
typedef __attribute__((ext_vector_type(4))) __bf16 bf16x4;
typedef __attribute__((ext_vector_type(4))) float  f32x4;

__device__ __forceinline__ void gl_lds16(const void* g, void* l) {
  __builtin_amdgcn_global_load_lds((const __attribute__((address_space(1))) void*)g,
                                   (__attribute__((address_space(3))) void*)l, 16, 0, 0);
}

__device__ __forceinline__ int imin(int a, int b) { return a < b ? a : b; }

// ---------------- zero out + counts ----------------
__global__ void zero_kernel(float* __restrict__ out, int* __restrict__ counts) {
  size_t stride = (size_t)gridDim.x * blockDim.x;
  size_t n4 = (size_t)T_TOK * DM / 4;
  for (size_t i = (size_t)blockIdx.x * blockDim.x + threadIdx.x; i < n4; i += stride) {
    float4 z = {0.f, 0.f, 0.f, 0.f};
    ((float4*)out)[i] = z;
  }
  if (blockIdx.x == 0 && threadIdx.x < NE) counts[threadIdx.x] = 0;
}

// ---------------- x fp32 -> bf16 ----------------
__global__ void cvt_x_kernel(const float* __restrict__ x, bf16* __restrict__ xb) {
  size_t stride = (size_t)gridDim.x * blockDim.x;
  size_t n4 = (size_t)T_TOK * DM / 4;
  for (size_t i = (size_t)blockIdx.x * blockDim.x + threadIdx.x; i < n4; i += stride) {
    float4 v = ((const float4*)x)[i];
    bf16x4 o;
    o[0] = (bf16)v.x; o[1] = (bf16)v.y; o[2] = (bf16)v.z; o[3] = (bf16)v.w;
    *(bf16x4*)(xb + 4 * i) = o;
  }
}

// ---------------- transpose + cvt: in [e][R][C] fp32 -> out [e][C][R] bf16 ----------------
__global__ void transpose_cvt_kernel(const float* __restrict__ in, bf16* __restrict__ out,
                                     int R, int C) {
  __shared__ float tile[32][33];
  int e = blockIdx.z;
  int c0 = blockIdx.x * 32, r0 = blockIdx.y * 32;
  int tx = threadIdx.x & 31, ty = threadIdx.x >> 5;  // 32 x 8
#pragma unroll
  for (int j = 0; j < 4; ++j)
    tile[ty + 8 * j][tx] = in[((size_t)e * R + (r0 + ty + 8 * j)) * C + (c0 + tx)];
  __syncthreads();
#pragma unroll
  for (int j = 0; j < 4; ++j)
    out[((size_t)e * C + (c0 + ty + 8 * j)) * R + (r0 + tx)] = (bf16)tile[tx][ty + 8 * j];
}

// ---------------- gating: logits (double), softmax, top-2, compaction ----------------
__global__ void gating_kernel(const float* __restrict__ x, const float* __restrict__ Wg,
                              const float* __restrict__ bg, int* __restrict__ counts,
                              int* __restrict__ tokl, float* __restrict__ wgt) {
  int t = blockIdx.x * 4 + (threadIdx.x >> 6);
  int lane = threadIdx.x & 63;
  if (t >= T_TOK) return;
  double acc[NE];
#pragma unroll
  for (int e = 0; e < NE; ++e) acc[e] = 0.0;
  const float* xr = x + (size_t)t * DM;
  for (int d = lane; d < DM; d += 64) {
    float xv = xr[d];
#pragma unroll
    for (int e = 0; e < NE; ++e) acc[e] += (double)xv * (double)Wg[d * NE + e];
  }
#pragma unroll
  for (int e = 0; e < NE; ++e)
    for (int o = 32; o > 0; o >>= 1) acc[e] += __shfl_down(acc[e], o, 64);
  if (lane == 0) {
    float l[NE], w[NE];
    float m = -1e30f;
#pragma unroll
    for (int e = 0; e < NE; ++e) { l[e] = (float)acc[e] + bg[e]; m = fmaxf(m, l[e]); }
    float s = 0.f;
#pragma unroll
    for (int e = 0; e < NE; ++e) { w[e] = __expf(l[e] - m); s += w[e]; }
    // use precise expf to stay close to numpy
    s = 0.f;
#pragma unroll
    for (int e = 0; e < NE; ++e) { w[e] = expf(l[e] - m); s += w[e]; }
    float inv = 1.f / s;
#pragma unroll
    for (int e = 0; e < NE; ++e) w[e] *= inv;
    int e1 = 0; float v1 = w[0];
#pragma unroll
    for (int e = 1; e < NE; ++e) if (w[e] > v1) { v1 = w[e]; e1 = e; }
    int e2 = -1; float v2 = -1.f;
#pragma unroll
    for (int e = 0; e < NE; ++e) if (e != e1 && w[e] > v2) { v2 = w[e]; e2 = e; }
    int s1 = atomicAdd(&counts[e1], 1);
    tokl[e1 * T_TOK + s1] = t; wgt[e1 * T_TOK + s1] = v1;
    int s2 = atomicAdd(&counts[e2], 1);
    tokl[e2 * T_TOK + s2] = t; wgt[e2 * T_TOK + s2] = v2;
  }
}

// ---------------- scan ----------------
__global__ void scan_kernel(const int* __restrict__ counts, int* __restrict__ offsets) {
  if (threadIdx.x == 0 && blockIdx.x == 0) {
    int s = 0;
#pragma unroll
    for (int e = 0; e < NE; ++e) { offsets[e] = s; s += counts[e]; }
    offsets[NE] = s;
  }
}

// ---------------- GEMM1: h = gelu(x[tok] @ W1[e] + b1[e]), bf16 out ----------------
__global__ __launch_bounds__(256) void gemm1_kernel(
    const bf16* __restrict__ xbf, const bf16* __restrict__ w1t,
    const float* __restrict__ b1, const int* __restrict__ counts,
    const int* __restrict__ offsets, const int* __restrict__ tokl,
    bf16* __restrict__ hbuf, int Hc, int cbase) {
  int e = blockIdx.z, rt = blockIdx.y, nt = blockIdx.x;
  int cnt = counts[e];
  if (rt * 128 >= cnt) return;
  __shared__ __align__(16) bf16 sA[128 * 32];
  __shared__ __align__(16) bf16 sB[128 * 32];
  int tid = threadIdx.x, lane = tid & 63, w = tid >> 6;
  int slot0 = w * 2048 + lane * 16;           // byte slot in 8KB tile
  int ra0 = slot0 >> 6, ko0 = slot0 & 63;     // row (64B rows), byte-in-row
  int ra1 = ra0 + 16, ko1 = ko0;
  int hoff = offsets[e];
  int r0 = imin(rt * 128 + ra0, cnt - 1);
  int r1 = imin(rt * 128 + ra1, cnt - 1);
  int t0 = tokl[e * T_TOK + r0];
  int t1 = tokl[e * T_TOK + r1];
  const char* ga0 = (const char*)(xbf + (size_t)t0 * DM) + ko0;
  const char* ga1 = (const char*)(xbf + (size_t)t1 * DM) + ko1;
  const char* gb0 = (const char*)(w1t + ((size_t)e * HD + cbase + nt * 128 + ra0) * DM) + ko0;
  const char* gb1 = (const char*)(w1t + ((size_t)e * HD + cbase + nt * 128 + ra1) * DM) + ko1;
  char* la = (char*)sA + w * 2048;
  char* lb = (char*)sB + w * 2048;
  f32x4 acc[4][4];
#pragma unroll
  for (int i = 0; i < 4; ++i)
#pragma unroll
    for (int j = 0; j < 4; ++j) acc[i][j] = {0.f, 0.f, 0.f, 0.f};
  int mw = (w & 1) * 64, nw = (w >> 1) * 64;
  const bf16* pa = sA + (size_t)(mw + (lane & 15)) * 32 + (lane >> 4) * 8;
  const bf16* pb = sB + (size_t)(nw + (lane & 15)) * 32 + (lane >> 4) * 8;
  for (int kk = 0; kk < DM; kk += 32) {
    gl_lds16(ga0 + kk * 2, la);
    gl_lds16(ga1 + kk * 2, la + 1024);
    gl_lds16(gb0 + kk * 2, lb);
    gl_lds16(gb1 + kk * 2, lb + 1024);
    __syncthreads();
    bf16x8 af[4], bfr[4];
#pragma unroll
    for (int i = 0; i < 4; ++i) af[i] = *(const bf16x8*)(pa + i * 16 * 32);
#pragma unroll
    for (int j = 0; j < 4; ++j) bfr[j] = *(const bf16x8*)(pb + j * 16 * 32);
#pragma unroll
    for (int i = 0; i < 4; ++i)
#pragma unroll
      for (int j = 0; j < 4; ++j)
        acc[i][j] = __builtin_amdgcn_mfma_f32_16x16x32_bf16(af[i], bfr[j], acc[i][j], 0, 0, 0);
    __syncthreads();
  }
  int colq = lane & 15, rowq = (lane >> 4) * 4;
  float b1v[4];
#pragma unroll
  for (int j = 0; j < 4; ++j)
    b1v[j] = b1[(size_t)e * HD + cbase + nt * 128 + nw + j * 16 + colq];
#pragma unroll
  for (int i = 0; i < 4; ++i) {
#pragma unroll
    for (int r = 0; r < 4; ++r) {
      int row_l = mw + i * 16 + rowq + r;
      int grow = rt * 128 + row_l;
      if (grow < cnt) {
        size_t hrow = (size_t)(hoff + grow) * Hc;
#pragma unroll
        for (int j = 0; j < 4; ++j) {
          float v = acc[i][j][r] + b1v[j];
          float g = 0.5f * v * (1.f + erff(v * 0.70710678118654752f));
          hbuf[hrow + nt * 128 + nw + j * 16 + colq] = (bf16)g;
        }
      }
    }
  }
}

// ---------------- GEMM2: out[tok] += w * (h @ W2[e] + b2[e]) ----------------
__global__ __launch_bounds__(256) void gemm2_kernel(
    const bf16* __restrict__ hbuf, const bf16* __restrict__ w2t,
    const float* __restrict__ b2, const int* __restrict__ counts,
    const int* __restrict__ offsets, const int* __restrict__ tokl,
    const float* __restrict__ wgt, float* __restrict__ out,
    int Hc, int cbase, float b2scale) {
  int e = blockIdx.z, rt = blockIdx.y, nt = blockIdx.x;
  int cnt = counts[e];
  if (rt * 128 >= cnt) return;
  __shared__ __align__(16) bf16 sA[128 * 32];
  __shared__ __align__(16) bf16 sB[128 * 32];
  int tid = threadIdx.x, lane = tid & 63, w = tid >> 6;
  int slot0 = w * 2048 + lane * 16;
  int ra0 = slot0 >> 6, ko0 = slot0 & 63;
  int ra1 = ra0 + 16, ko1 = ko0;
  int hoff = offsets[e];
  int r0 = imin(rt * 128 + ra0, cnt - 1);
  int r1 = imin(rt * 128 + ra1, cnt - 1);
  const char* ga0 = (const char*)(hbuf + (size_t)(hoff + r0) * Hc) + ko0;
  const char* ga1 = (const char*)(hbuf + (size_t)(hoff + r1) * Hc) + ko1;
  const char* gb0 = (const char*)(w2t + ((size_t)e * DM + nt * 128 + ra0) * HD + cbase) + ko0;
  const char* gb1 = (const char*)(w2t + ((size_t)e * DM + nt * 128 + ra1) * HD + cbase) + ko1;
  char* la = (char*)sA + w * 2048;
  char* lb = (char*)sB + w * 2048;
  f32x4 acc[4][4];
#pragma unroll
  for (int i = 0; i < 4; ++i)
#pragma unroll
    for (int j = 0; j < 4; ++j) acc[i][j] = {0.f, 0.f, 0.f, 0.f};
  int mw = (w & 1) * 64, nw = (w >> 1) * 64;
  const bf16* pa = sA + (size_t)(mw + (lane & 15)) * 32 + (lane >> 4) * 8;
  const bf16* pb = sB + (size_t)(nw + (lane & 15)) * 32 + (lane >> 4) * 8;
  for (int kk = 0; kk < Hc; kk += 32) {
    gl_lds16(ga0 + kk * 2, la);
    gl_lds16(ga1 + kk * 2, la + 1024);
    gl_lds16(gb0 + kk * 2, lb);
    gl_lds16(gb1 + kk * 2, lb + 1024);
    __syncthreads();
    bf16x8 af[4], bfr[4];
#pragma unroll
    for (int i = 0; i < 4; ++i) af[i] = *(const bf16x8*)(pa + i * 16 * 32);
#pragma unroll
    for (int j = 0; j < 4; ++j) bfr[j] = *(const bf16x8*)(pb + j * 16 * 32);
#pragma unroll
    for (int i = 0; i < 4; ++i)
#pragma unroll
      for (int j = 0; j < 4; ++j)
        acc[i][j] = __builtin_amdgcn_mfma_f32_16x16x32_bf16(af[i], bfr[j], acc[i][j], 0, 0, 0);
    __syncthreads();
  }
  int colq = lane & 15, rowq = (lane >> 4) * 4;
  float b2v[4];
#pragma unroll
  for (int j = 0; j < 4; ++j)
    b2v[j] = b2[(size_t)e * DM + nt * 128 + nw + j * 16 + colq] * b2scale;
#pragma unroll
  for (int i = 0; i < 4; ++i) {
#pragma unroll
    for (int r = 0; r < 4; ++r) {
      int row_l = mw + i * 16 + rowq + r;
      int grow = rt * 128 + row_l;
      if (grow < cnt) {
        float wv = wgt[e * T_TOK + grow];
        int tk = tokl[e * T_TOK + grow];
        float* orow = out + (size_t)tk * DM + nt * 128 + nw;
#pragma unroll
        for (int j = 0; j < 4; ++j)
          atomicAdd(orow + j * 16 + colq, wv * (acc[i][j][r] + b2v[j]));
      }
    }
  }
}

extern "C" void kernel_launch(void* const* d_in, const int* in_sizes, int n_in,
                              void* d_out, int out_size, void* d_ws, size_t ws_size,
                              hipStream_t stream) {
  const float* x  = (const float*)d_in[0];
  const float* Wg = (const float*)d_in[1];
  const float* bg = (const float*)d_in[2];
  const float* W1 = (const float*)d_in[3];
  const float* b1 = (const float*)d_in[4];
  const float* W2 = (const float*)d_in[5];
  const float* b2 = (const float*)d_in[6];
  float* out = (float*)d_out;

  char* ws = (char*)d_ws;
  size_t off = 0;
  auto alloc = [&](size_t bytes) -> void* {
    void* p = ws + off;
    off = (off + bytes + 255) & ~(size_t)255;
    return p;
  };
  int*   counts  = (int*)alloc(NE * 4);
  int*   offsets = (int*)alloc((NE + 1) * 4);
  int*   tokl    = (int*)alloc((size_t)NE * T_TOK * 4);
  float* wgt     = (float*)alloc((size_t)NE * T_TOK * 4);
  bf16*  xbf     = (bf16*)alloc((size_t)T_TOK * DM * 2);
  bf16*  w1t     = (bf16*)alloc((size_t)NE * HD * DM * 2);
  bf16*  w2t     = (bf16*)alloc((size_t)NE * DM * HD * 2);
  size_t remain = ws_size > off ? ws_size - off : 0;
  int Hc = HD;
  while (Hc > 128 && (size_t)2 * T_TOK * Hc * 2 > remain) Hc >>= 1;  // h rows total = 2*T
  bf16* hbuf = (bf16*)alloc((size_t)2 * T_TOK * Hc * 2);

  zero_kernel<<<4096, 256, 0, stream>>>(out, counts);
  cvt_x_kernel<<<2048, 256, 0, stream>>>(x, xbf);
  transpose_cvt_kernel<<<dim3(HD / 32, DM / 32, NE), 256, 0, stream>>>(W1, w1t, DM, HD);
  transpose_cvt_kernel<<<dim3(DM / 32, HD / 32, NE), 256, 0, stream>>>(W2, w2t, HD, DM);
  gating_kernel<<<T_TOK / 4, 256, 0, stream>>>(x, Wg, bg, counts, tokl, wgt);
  scan_kernel<<<1, 64, 0, stream>>>(counts, offsets);

  int nchunk = HD / Hc;
  for (int c = 0; c < nchunk; ++c) {
    gemm1_kernel<<<dim3(Hc / 128, T_TOK / 128, NE), 256, 0, stream>>>(
        xbf, w1t, b1, counts, offsets, tokl, hbuf, Hc, c * Hc);
    gemm2_kernel<<<dim3(DM / 128, T_TOK / 128, NE), 256, 0, stream>>>(
        hbuf, w2t, b2, counts, offsets, tokl, wgt, out, Hc, c * Hc, c == 0 ? 1.f : 0.f);
  }
}

// Round 2
// 1027.619 us; speedup vs baseline: 1.0098x; 1.0098x over previous
//
#include <hip/hip_runtime.h>
#include <hip/hip_bf16.h>
#include <math.h>

// Problem constants (B=4, S=2048 -> T=8192 tokens)
#define T_TOK 8192
#define DM    1024
#define NE    8
#define HD    4096

typedef __bf16 bf16;
typedef __attribute__((ext_vector_type(8))) __bf16 bf16x8;
typedef __attribute__((ext_vector_type(4))) __bf16 bf16x4;
typedef __attribute__((ext_vector_type(4))) float  f32x4;

__device__ __forceinline__ void gl_lds16(const void* g, void* l) {
  __builtin_amdgcn_global_load_lds((const __attribute__((address_space(1))) void*)g,
                                   (__attribute__((address_space(3))) void*)l, 16, 0, 0);
}

__device__ __forceinline__ int imin(int a, int b) { return a < b ? a : b; }

// ---------------- zero out + counts ----------------
__global__ void zero_kernel(float* __restrict__ out, int* __restrict__ counts) {
  size_t stride = (size_t)gridDim.x * blockDim.x;
  size_t n4 = (size_t)T_TOK * DM / 4;
  for (size_t i = (size_t)blockIdx.x * blockDim.x + threadIdx.x; i < n4; i += stride) {
    float4 z = {0.f, 0.f, 0.f, 0.f};
    ((float4*)out)[i] = z;
  }
  if (blockIdx.x == 0 && threadIdx.x < NE) counts[threadIdx.x] = 0;
}

// ---------------- x fp32 -> bf16 ----------------
__global__ void cvt_x_kernel(const float* __restrict__ x, bf16* __restrict__ xb) {
  size_t stride = (size_t)gridDim.x * blockDim.x;
  size_t n4 = (size_t)T_TOK * DM / 4;
  for (size_t i = (size_t)blockIdx.x * blockDim.x + threadIdx.x; i < n4; i += stride) {
    float4 v = ((const float4*)x)[i];
    bf16x4 o;
    o[0] = (bf16)v.x; o[1] = (bf16)v.y; o[2] = (bf16)v.z; o[3] = (bf16)v.w;
    *(bf16x4*)(xb + 4 * i) = o;
  }
}

// ---------------- transpose + cvt: in [e][R][C] fp32 -> out [e][C][R] bf16 ----------------
__global__ void transpose_cvt_kernel(const float* __restrict__ in, bf16* __restrict__ out,
                                     int R, int C) {
  __shared__ float tile[32][33];
  int e = blockIdx.z;
  int c0 = blockIdx.x * 32, r0 = blockIdx.y * 32;
  int tx = threadIdx.x & 31, ty = threadIdx.x >> 5;  // 32 x 8
#pragma unroll
  for (int j = 0; j < 4; ++j)
    tile[ty + 8 * j][tx] = in[((size_t)e * R + (r0 + ty + 8 * j)) * C + (c0 + tx)];
  __syncthreads();
#pragma unroll
  for (int j = 0; j < 4; ++j)
    out[((size_t)e * C + (c0 + ty + 8 * j)) * R + (r0 + tx)] = (bf16)tile[tx][ty + 8 * j];
}

// ---------------- gating: logits (double), softmax, top-2, compaction ----------------
__global__ void gating_kernel(const float* __restrict__ x, const float* __restrict__ Wg,
                              const float* __restrict__ bg, int* __restrict__ counts,
                              int* __restrict__ tokl, float* __restrict__ wgt) {
  int t = blockIdx.x * 4 + (threadIdx.x >> 6);
  int lane = threadIdx.x & 63;
  if (t >= T_TOK) return;
  double acc[NE];
#pragma unroll
  for (int e = 0; e < NE; ++e) acc[e] = 0.0;
  const float* xr = x + (size_t)t * DM;
  for (int d = lane; d < DM; d += 64) {
    float xv = xr[d];
#pragma unroll
    for (int e = 0; e < NE; ++e) acc[e] += (double)xv * (double)Wg[d * NE + e];
  }
#pragma unroll
  for (int e = 0; e < NE; ++e)
    for (int o = 32; o > 0; o >>= 1) acc[e] += __shfl_down(acc[e], o, 64);
  if (lane == 0) {
    float l[NE], w[NE];
    float m = -1e30f;
#pragma unroll
    for (int e = 0; e < NE; ++e) { l[e] = (float)acc[e] + bg[e]; m = fmaxf(m, l[e]); }
    float s = 0.f;
#pragma unroll
    for (int e = 0; e < NE; ++e) { w[e] = expf(l[e] - m); s += w[e]; }
    float inv = 1.f / s;
#pragma unroll
    for (int e = 0; e < NE; ++e) w[e] *= inv;
    int e1 = 0; float v1 = w[0];
#pragma unroll
    for (int e = 1; e < NE; ++e) if (w[e] > v1) { v1 = w[e]; e1 = e; }
    int e2 = -1; float v2 = -1.f;
#pragma unroll
    for (int e = 0; e < NE; ++e) if (e != e1 && w[e] > v2) { v2 = w[e]; e2 = e; }
    int s1 = atomicAdd(&counts[e1], 1);
    tokl[e1 * T_TOK + s1] = t; wgt[e1 * T_TOK + s1] = v1;
    int s2 = atomicAdd(&counts[e2], 1);
    tokl[e2 * T_TOK + s2] = t; wgt[e2 * T_TOK + s2] = v2;
  }
}

// ---------------- scan ----------------
__global__ void scan_kernel(const int* __restrict__ counts, int* __restrict__ offsets) {
  if (threadIdx.x == 0 && blockIdx.x == 0) {
    int s = 0;
#pragma unroll
    for (int e = 0; e < NE; ++e) { offsets[e] = s; s += counts[e]; }
    offsets[NE] = s;
  }
}

// ---------------- GEMM1: h = gelu(x[tok] @ W1[e] + b1[e]), bf16 out ----------------
// Flat grid, e = bid % NE so each expert pins to one XCD (bid%8 round-robin).
__global__ __launch_bounds__(256) void gemm1_kernel(
    const bf16* __restrict__ xbf, const bf16* __restrict__ w1t,
    const float* __restrict__ b1, const int* __restrict__ counts,
    const int* __restrict__ offsets, const int* __restrict__ tokl,
    bf16* __restrict__ hbuf, int Hc, int cbase) {
  int bid = blockIdx.x;
  int e = bid % NE;
  int pe = bid / NE;
  int NT = Hc / 128;
  int nt = pe % NT, rt = pe / NT;
  int cnt = counts[e];
  if (rt * 128 >= cnt) return;
  __shared__ __align__(16) bf16 sA[128 * 32];
  __shared__ __align__(16) bf16 sB[128 * 32];
  int tid = threadIdx.x, lane = tid & 63, w = tid >> 6;
  int slot0 = w * 2048 + lane * 16;           // byte slot in 8KB tile
  int ra0 = slot0 >> 6, ko0 = slot0 & 63;     // row (64B rows), byte-in-row
  int ra1 = ra0 + 16, ko1 = ko0;
  int hoff = offsets[e];
  int r0 = imin(rt * 128 + ra0, cnt - 1);
  int r1 = imin(rt * 128 + ra1, cnt - 1);
  int t0 = tokl[e * T_TOK + r0];
  int t1 = tokl[e * T_TOK + r1];
  const char* ga0 = (const char*)(xbf + (size_t)t0 * DM) + ko0;
  const char* ga1 = (const char*)(xbf + (size_t)t1 * DM) + ko1;
  const char* gb0 = (const char*)(w1t + ((size_t)e * HD + cbase + nt * 128 + ra0) * DM) + ko0;
  const char* gb1 = (const char*)(w1t + ((size_t)e * HD + cbase + nt * 128 + ra1) * DM) + ko1;
  char* la = (char*)sA + w * 2048;
  char* lb = (char*)sB + w * 2048;
  f32x4 acc[4][4];
#pragma unroll
  for (int i = 0; i < 4; ++i)
#pragma unroll
    for (int j = 0; j < 4; ++j) acc[i][j] = {0.f, 0.f, 0.f, 0.f};
  int mw = (w & 1) * 64, nw = (w >> 1) * 64;
  const bf16* pa = sA + (size_t)(mw + (lane & 15)) * 32 + (lane >> 4) * 8;
  const bf16* pb = sB + (size_t)(nw + (lane & 15)) * 32 + (lane >> 4) * 8;
  for (int kk = 0; kk < DM; kk += 32) {
    gl_lds16(ga0 + kk * 2, la);
    gl_lds16(ga1 + kk * 2, la + 1024);
    gl_lds16(gb0 + kk * 2, lb);
    gl_lds16(gb1 + kk * 2, lb + 1024);
    __syncthreads();
    bf16x8 af[4], bfr[4];
#pragma unroll
    for (int i = 0; i < 4; ++i) af[i] = *(const bf16x8*)(pa + i * 16 * 32);
#pragma unroll
    for (int j = 0; j < 4; ++j) bfr[j] = *(const bf16x8*)(pb + j * 16 * 32);
#pragma unroll
    for (int i = 0; i < 4; ++i)
#pragma unroll
      for (int j = 0; j < 4; ++j)
        acc[i][j] = __builtin_amdgcn_mfma_f32_16x16x32_bf16(af[i], bfr[j], acc[i][j], 0, 0, 0);
    __syncthreads();
  }
  int colq = lane & 15, rowq = (lane >> 4) * 4;
  float b1v[4];
#pragma unroll
  for (int j = 0; j < 4; ++j)
    b1v[j] = b1[(size_t)e * HD + cbase + nt * 128 + nw + j * 16 + colq];
#pragma unroll
  for (int i = 0; i < 4; ++i) {
#pragma unroll
    for (int r = 0; r < 4; ++r) {
      int row_l = mw + i * 16 + rowq + r;
      int grow = rt * 128 + row_l;
      if (grow < cnt) {
        size_t hrow = (size_t)(hoff + grow) * Hc;
#pragma unroll
        for (int j = 0; j < 4; ++j) {
          float v = acc[i][j][r] + b1v[j];
          float g = 0.5f * v * (1.f + erff(v * 0.70710678118654752f));
          hbuf[hrow + nt * 128 + nw + j * 16 + colq] = (bf16)g;
        }
      }
    }
  }
}

// ---------------- GEMM2: out[tok] += w * (h @ W2[e] + b2[e]) ----------------
__global__ __launch_bounds__(256) void gemm2_kernel(
    const bf16* __restrict__ hbuf, const bf16* __restrict__ w2t,
    const float* __restrict__ b2, const int* __restrict__ counts,
    const int* __restrict__ offsets, const int* __restrict__ tokl,
    const float* __restrict__ wgt, float* __restrict__ out,
    int Hc, int cbase, float b2scale) {
  int bid = blockIdx.x;
  int e = bid % NE;
  int pe = bid / NE;
  const int NT = DM / 128;
  int nt = pe % NT, rt = pe / NT;
  int cnt = counts[e];
  if (rt * 128 >= cnt) return;
  __shared__ __align__(16) bf16 sA[128 * 32];
  __shared__ __align__(16) bf16 sB[128 * 32];
  int tid = threadIdx.x, lane = tid & 63, w = tid >> 6;
  int slot0 = w * 2048 + lane * 16;
  int ra0 = slot0 >> 6, ko0 = slot0 & 63;
  int ra1 = ra0 + 16, ko1 = ko0;
  int hoff = offsets[e];
  int r0 = imin(rt * 128 + ra0, cnt - 1);
  int r1 = imin(rt * 128 + ra1, cnt - 1);
  const char* ga0 = (const char*)(hbuf + (size_t)(hoff + r0) * Hc) + ko0;
  const char* ga1 = (const char*)(hbuf + (size_t)(hoff + r1) * Hc) + ko1;
  const char* gb0 = (const char*)(w2t + ((size_t)e * DM + nt * 128 + ra0) * HD + cbase) + ko0;
  const char* gb1 = (const char*)(w2t + ((size_t)e * DM + nt * 128 + ra1) * HD + cbase) + ko1;
  char* la = (char*)sA + w * 2048;
  char* lb = (char*)sB + w * 2048;
  f32x4 acc[4][4];
#pragma unroll
  for (int i = 0; i < 4; ++i)
#pragma unroll
    for (int j = 0; j < 4; ++j) acc[i][j] = {0.f, 0.f, 0.f, 0.f};
  int mw = (w & 1) * 64, nw = (w >> 1) * 64;
  const bf16* pa = sA + (size_t)(mw + (lane & 15)) * 32 + (lane >> 4) * 8;
  const bf16* pb = sB + (size_t)(nw + (lane & 15)) * 32 + (lane >> 4) * 8;
  for (int kk = 0; kk < Hc; kk += 32) {
    gl_lds16(ga0 + kk * 2, la);
    gl_lds16(ga1 + kk * 2, la + 1024);
    gl_lds16(gb0 + kk * 2, lb);
    gl_lds16(gb1 + kk * 2, lb + 1024);
    __syncthreads();
    bf16x8 af[4], bfr[4];
#pragma unroll
    for (int i = 0; i < 4; ++i) af[i] = *(const bf16x8*)(pa + i * 16 * 32);
#pragma unroll
    for (int j = 0; j < 4; ++j) bfr[j] = *(const bf16x8*)(pb + j * 16 * 32);
#pragma unroll
    for (int i = 0; i < 4; ++i)
#pragma unroll
      for (int j = 0; j < 4; ++j)
        acc[i][j] = __builtin_amdgcn_mfma_f32_16x16x32_bf16(af[i], bfr[j], acc[i][j], 0, 0, 0);
    __syncthreads();
  }
  int colq = lane & 15, rowq = (lane >> 4) * 4;
  float b2v[4];
#pragma unroll
  for (int j = 0; j < 4; ++j)
    b2v[j] = b2[(size_t)e * DM + nt * 128 + nw + j * 16 + colq] * b2scale;
#pragma unroll
  for (int i = 0; i < 4; ++i) {
#pragma unroll
    for (int r = 0; r < 4; ++r) {
      int row_l = mw + i * 16 + rowq + r;
      int grow = rt * 128 + row_l;
      if (grow < cnt) {
        float wv = wgt[e * T_TOK + grow];
        int tk = tokl[e * T_TOK + grow];
        float* orow = out + (size_t)tk * DM + nt * 128 + nw;
#pragma unroll
        for (int j = 0; j < 4; ++j)
          atomicAdd(orow + j * 16 + colq, wv * (acc[i][j][r] + b2v[j]));
      }
    }
  }
}

extern "C" void kernel_launch(void* const* d_in, const int* in_sizes, int n_in,
                              void* d_out, int out_size, void* d_ws, size_t ws_size,
                              hipStream_t stream) {
  const float* x  = (const float*)d_in[0];
  const float* Wg = (const float*)d_in[1];
  const float* bg = (const float*)d_in[2];
  const float* W1 = (const float*)d_in[3];
  const float* b1 = (const float*)d_in[4];
  const float* W2 = (const float*)d_in[5];
  const float* b2 = (const float*)d_in[6];
  float* out = (float*)d_out;

  char* ws = (char*)d_ws;
  size_t off = 0;
  auto alloc = [&](size_t bytes) -> void* {
    void* p = ws + off;
    off = (off + bytes + 255) & ~(size_t)255;
    return p;
  };
  int*   counts  = (int*)alloc(NE * 4);
  int*   offsets = (int*)alloc((NE + 1) * 4);
  int*   tokl    = (int*)alloc((size_t)NE * T_TOK * 4);
  float* wgt     = (float*)alloc((size_t)NE * T_TOK * 4);
  bf16*  xbf     = (bf16*)alloc((size_t)T_TOK * DM * 2);
  bf16*  w1t     = (bf16*)alloc((size_t)NE * HD * DM * 2);
  bf16*  w2t     = (bf16*)alloc((size_t)NE * DM * HD * 2);
  size_t remain = ws_size > off ? ws_size - off : 0;
  int Hc = HD;
  while (Hc > 128 && (size_t)2 * T_TOK * Hc * 2 > remain) Hc >>= 1;  // h rows total = 2*T
  bf16* hbuf = (bf16*)alloc((size_t)2 * T_TOK * Hc * 2);

  zero_kernel<<<4096, 256, 0, stream>>>(out, counts);
  cvt_x_kernel<<<2048, 256, 0, stream>>>(x, xbf);
  transpose_cvt_kernel<<<dim3(HD / 32, DM / 32, NE), 256, 0, stream>>>(W1, w1t, DM, HD);
  transpose_cvt_kernel<<<dim3(DM / 32, HD / 32, NE), 256, 0, stream>>>(W2, w2t, HD, DM);
  gating_kernel<<<T_TOK / 4, 256, 0, stream>>>(x, Wg, bg, counts, tokl, wgt);
  scan_kernel<<<1, 64, 0, stream>>>(counts, offsets);

  int nchunk = HD / Hc;
  for (int c = 0; c < nchunk; ++c) {
    // flat grid: e = bid % NE -> expert pinned to one XCD (bid%8 round-robin)
    gemm1_kernel<<<NE * (Hc / 128) * (T_TOK / 128), 256, 0, stream>>>(
        xbf, w1t, b1, counts, offsets, tokl, hbuf, Hc, c * Hc);
    gemm2_kernel<<<NE * (DM / 128) * (T_TOK / 128), 256, 0, stream>>>(
        hbuf, w2t, b2, counts, offsets, tokl, wgt, out, Hc, c * Hc, c == 0 ? 1.f : 0.f);
  }
}